// Round 16
// baseline (325.553 us; speedup 1.0000x reference)
//
#include <hip/hip_runtime.h>
#include <hip/hip_bf16.h>

typedef __hip_bfloat16 bf16;
typedef __attribute__((ext_vector_type(8))) __bf16 bf16x8;
typedef __attribute__((ext_vector_type(4))) float f32x4;

constexpr int TT = 2048;   // sequence length
constexpr int HD = 2048;   // hidden dim
constexpr int VD = 4096;   // value dim
constexpr int KD = 128;    // key dim per head
constexpr int NH = 16;     // heads
constexpr int DH = 256;    // head dim of v
constexpr float K_SCALING = 0.08838834764831845f;  // 128^-0.5

__device__ __forceinline__ bf16 f2bf(float x) { return __float2bfloat16(x); }
__device__ __forceinline__ unsigned short f2bfu(float x) {
    bf16 b = __float2bfloat16(x);
    return *reinterpret_cast<unsigned short*>(&b);
}
__device__ __forceinline__ float bf2f(unsigned short u) {
    unsigned int x = ((unsigned int)u) << 16;
    return __uint_as_float(x);
}

// ---------------------------------------------------------------------------
// Batched: all 5 weight transposes (8192 tiles) + hidden f32->bf16 (512 blocks)
// ---------------------------------------------------------------------------
__global__ __launch_bounds__(256) void transpose_all_k(
    const float* __restrict__ Wq, const float* __restrict__ Wk,
    const float* __restrict__ Wv, const float* __restrict__ Wg,
    const float* __restrict__ Wo, bf16* __restrict__ Wcat, bf16* __restrict__ WoT,
    const float* __restrict__ hidden, bf16* __restrict__ hb)
{
    __shared__ unsigned short sT[64 * 72];
    int t2 = blockIdx.x;
    if (t2 >= 8192) {
        const int b = t2 - 8192;
        const size_t base = (size_t)b * 8192;
#pragma unroll
        for (int j = 0; j < 8; ++j) {
            const size_t i = base + j * 1024 + threadIdx.x * 4;
            float4 v = *(const float4*)(hidden + i);
            bf16 tmp[4] = {f2bf(v.x), f2bf(v.y), f2bf(v.z), f2bf(v.w)};
            *(uint2*)(hb + i) = *(const uint2*)tmp;
        }
        return;
    }
    const float* src;
    bf16* dst;
    int R, C;
    if (t2 < 1024)      { src = Wq; dst = Wcat;                     R = 2048; C = 2048; }
    else if (t2 < 2048) { src = Wk; dst = Wcat + (size_t)2048 * HD; R = 2048; C = 2048; t2 -= 1024; }
    else if (t2 < 4096) { src = Wv; dst = Wcat + (size_t)4096 * HD; R = 2048; C = 4096; t2 -= 2048; }
    else if (t2 < 6144) { src = Wg; dst = Wcat + (size_t)8192 * HD; R = 2048; C = 4096; t2 -= 4096; }
    else                { src = Wo; dst = WoT;                      R = 4096; C = 2048; t2 -= 6144; }
    const int xt = C >> 6;
    const int x0 = (t2 % xt) * 64;
    const int y0 = (t2 / xt) * 64;

    const int t = threadIdx.x;
    {
        const int r = t >> 2;
        const int c0 = (t & 3) << 4;
        const float* s = src + (size_t)(y0 + r) * C + x0 + c0;
        unsigned short e[16];
#pragma unroll
        for (int j = 0; j < 4; ++j) {
            float4 v = *(const float4*)(s + j * 4);
            e[j * 4 + 0] = f2bfu(v.x);
            e[j * 4 + 1] = f2bfu(v.y);
            e[j * 4 + 2] = f2bfu(v.z);
            e[j * 4 + 3] = f2bfu(v.w);
        }
#pragma unroll
        for (int i = 0; i < 16; ++i) {
            const int c = c0 + i;
            sT[c * 72 + (r ^ (((c >> 3) & 7) << 3))] = e[i];
        }
    }
    __syncthreads();
    {
        const int c = t >> 2;
        const int r0 = (t & 3) << 4;
        const int xs = ((c >> 3) & 7) << 3;
#pragma unroll
        for (int s2 = 0; s2 < 16; s2 += 8) {
            bf16x8 v = *(const bf16x8*)&sT[c * 72 + ((r0 + s2) ^ xs)];
            *(bf16x8*)&dst[(size_t)(x0 + c) * R + y0 + r0 + s2] = v;
        }
    }
}

// ---------------------------------------------------------------------------
// Fused QKVG GEMM, 8-phase 256x192 schedule (BK=64, 2 K-tiles/iter).
// V segment written TRANSPOSED directly to vT (per-lane 8B stores).
// ---------------------------------------------------------------------------
#define GLL(gptr, lptr) __builtin_amdgcn_global_load_lds( \
    (const __attribute__((address_space(1))) void*)(gptr), \
    (__attribute__((address_space(3))) void*)(lptr), 16, 0, 0)

#define STA(bufs, u, k1) GLL(gA0 + (size_t)((u) * 64) * HD + (k1), sA + (bufs) + (u) * 4096 + tid * 8)
#define STB(bufs, u, k1) GLL(gB0 + (size_t)((u) * 64) * HD + (k1), sB + (bufs) + (u) * 4096 + tid * 8)

#define WAIT6 asm volatile("s_waitcnt vmcnt(6)" ::: "memory")
#define WAIT0V asm volatile("s_waitcnt vmcnt(0)" ::: "memory")
#define MEMF asm volatile("" ::: "memory")
#define BAR __builtin_amdgcn_s_barrier()

#define LDA(dst, cb, qm) \
    _Pragma("unroll") for (int mi = 0; mi < 4; ++mi) { \
        const int r_ = wr * 128 + (qm) * 64 + mi * 16 + lr; \
        _Pragma("unroll") for (int ks = 0; ks < 2; ++ks) \
            dst[mi][ks] = *(const bf16x8*)&sA[(cb) + r_ * 64 + (((ks * 4 + g) ^ (lr & 7)) << 3)]; \
    }

#define LDB01(dst, cb) \
    _Pragma("unroll") for (int ni = 0; ni < 2; ++ni) { \
        const int n_ = wcn * 48 + ni * 16 + lr; \
        _Pragma("unroll") for (int ks = 0; ks < 2; ++ks) \
            dst[ni][ks] = *(const bf16x8*)&sB[(cb) + n_ * 64 + (((ks * 4 + g) ^ (lr & 7)) << 3)]; \
    }

#define LDB2(dst, cb) { \
        const int n_ = wcn * 48 + 32 + lr; \
        _Pragma("unroll") for (int ks = 0; ks < 2; ++ks) \
            dst[ks] = *(const bf16x8*)&sB[(cb) + n_ * 64 + (((ks * 4 + g) ^ (lr & 7)) << 3)]; \
    }

#define Q00 __builtin_amdgcn_s_setprio(1); \
    _Pragma("unroll") for (int mi = 0; mi < 4; ++mi) \
        _Pragma("unroll") for (int ni = 0; ni < 2; ++ni) \
            _Pragma("unroll") for (int ks = 0; ks < 2; ++ks) \
                acc[mi][ni] = __builtin_amdgcn_mfma_f32_16x16x32_bf16(ra0[mi][ks], rb[ni][ks], acc[mi][ni], 0, 0, 0); \
    __builtin_amdgcn_s_setprio(0);
#define Q10 __builtin_amdgcn_s_setprio(1); \
    _Pragma("unroll") for (int mi = 0; mi < 4; ++mi) \
        _Pragma("unroll") for (int ni = 0; ni < 2; ++ni) \
            _Pragma("unroll") for (int ks = 0; ks < 2; ++ks) \
                acc[4 + mi][ni] = __builtin_amdgcn_mfma_f32_16x16x32_bf16(ra1[mi][ks], rb[ni][ks], acc[4 + mi][ni], 0, 0, 0); \
    __builtin_amdgcn_s_setprio(0);
#define Q11 __builtin_amdgcn_s_setprio(1); \
    _Pragma("unroll") for (int mi = 0; mi < 4; ++mi) \
        _Pragma("unroll") for (int ks = 0; ks < 2; ++ks) \
            acc[4 + mi][2] = __builtin_amdgcn_mfma_f32_16x16x32_bf16(ra1[mi][ks], rb2[ks], acc[4 + mi][2], 0, 0, 0); \
    __builtin_amdgcn_s_setprio(0);
#define Q01 __builtin_amdgcn_s_setprio(1); \
    _Pragma("unroll") for (int mi = 0; mi < 4; ++mi) \
        _Pragma("unroll") for (int ks = 0; ks < 2; ++ks) \
            acc[mi][2] = __builtin_amdgcn_mfma_f32_16x16x32_bf16(ra0[mi][ks], rb2[ks], acc[mi][2], 0, 0, 0); \
    __builtin_amdgcn_s_setprio(0);

__global__ __launch_bounds__(512, 2) void gemm_qkvg_k(
    const bf16* __restrict__ Ag, const bf16* __restrict__ Bg,
    const float* __restrict__ bq, const float* __restrict__ bk,
    const float* __restrict__ bvp, const float* __restrict__ bg,
    const float* __restrict__ sinT, const float* __restrict__ cosT,
    bf16* __restrict__ qr, bf16* __restrict__ kr,
    bf16* __restrict__ vT, bf16* __restrict__ sg)
{
    __shared__ unsigned short sA[2 * 256 * 64];
    __shared__ unsigned short sB[2 * 192 * 64];
    constexpr int BUFA = 16384, BUFB = 12288;

    const int tid = threadIdx.x;
    const int lane = tid & 63;
    const int w = tid >> 6;
    const int wr = w >> 2;
    const int wcn = w & 3;
    const int lr = lane & 15;
    const int g = lane >> 4;

    const int flat = blockIdx.x;
    const int swz = (flat & 7) * 64 + (flat >> 3);
    const int brow = (swz & 7) * 256;
    const int bcol = (swz >> 3) * 192;

    const bf16* gA0 = Ag + (size_t)(brow + (tid >> 3)) * HD + (((tid & 7) ^ ((tid >> 3) & 7)) << 3);
    const bf16* gB0 = Bg + (size_t)(bcol + (tid >> 3)) * HD + (((tid & 7) ^ ((tid >> 3) & 7)) << 3);

    f32x4 acc[8][3] = {};
    bf16x8 ra0[4][2], ra1[4][2], rb[2][2], rb2[2];

    STA(0, 0, 0); STA(0, 1, 0); STA(0, 2, 0); STA(0, 3, 0);
    STB(0, 0, 0); STB(0, 1, 0); STB(0, 2, 0);
    STA(BUFA, 0, 64); STA(BUFA, 1, 64); STA(BUFA, 2, 64); STA(BUFA, 3, 64);
    STB(BUFB, 0, 64); STB(BUFB, 1, 64);
    WAIT6; MEMF; BAR;

    for (int I = 0; I < 15; ++I) {
        const int kB1 = I * 128 + 64;
        const int kN2 = I * 128 + 128;
        const int kN3 = I * 128 + 192;
        LDA(ra0, 0, 0) LDB01(rb, 0)
        STB(BUFB, 2, kB1);
        MEMF; BAR; Q00 BAR;
        LDA(ra1, 0, 1)
        STA(0, 0, kN2); STA(0, 2, kN2);
        MEMF; BAR; Q10 BAR;
        LDB2(rb2, 0)
        STA(0, 1, kN2); STA(0, 3, kN2);
        MEMF; BAR; Q11 BAR;
        STB(0, 0, kN2); STB(0, 1, kN2);
        WAIT6; MEMF; BAR; Q01 BAR;
        LDA(ra0, BUFA, 0) LDB01(rb, BUFB)
        STB(0, 2, kN2);
        MEMF; BAR; Q00 BAR;
        LDA(ra1, BUFA, 1)
        STA(BUFA, 0, kN3); STA(BUFA, 2, kN3);
        MEMF; BAR; Q10 BAR;
        LDB2(rb2, BUFB)
        STA(BUFA, 1, kN3); STA(BUFA, 3, kN3);
        MEMF; BAR; Q11 BAR;
        STB(BUFB, 0, kN3); STB(BUFB, 1, kN3);
        WAIT6; MEMF; BAR; Q01 BAR;
    }
    {
        LDA(ra0, 0, 0) LDB01(rb, 0)
        STB(BUFB, 2, 1984);
        MEMF; BAR; Q00 BAR;
        LDA(ra1, 0, 1)
        MEMF; BAR; Q10 BAR;
        LDB2(rb2, 0)
        MEMF; BAR; Q11 BAR;
        WAIT0V; MEMF; BAR; Q01 BAR;
        LDA(ra0, BUFA, 0) LDB01(rb, BUFB)
        Q00
        LDA(ra1, BUFA, 1)
        Q10
        LDB2(rb2, BUFB)
        Q11
        Q01
    }

#pragma unroll
    for (int M = 0; M < 8; ++M) {
        const int row = brow + wr * 128 + (M >> 2) * 64 + (M & 3) * 16 + g * 4;
#pragma unroll
        for (int f = 0; f < 3; ++f) {
            const int colg = bcol + wcn * 48 + f * 16 + lr;
            if (colg < 4096) {
                const bool isK = (colg >= 2048);
                const int col = colg - (isK ? 2048 : 0);
                const float bvv = (isK ? bk : bq)[col];
                const float scale = isK ? K_SCALING : 1.f;
                bf16* outb = isK ? kr : qr;
                const int d = col & (KD - 1);
#pragma unroll
                for (int r = 0; r < 4; ++r) {
                    float v = (acc[M][f][r] + bvv) * scale;
                    float o = __shfl_xor(v, 1);
                    float rot = (col & 1) ? o : -o;
                    outb[(size_t)(row + r) * HD + col] =
                        f2bf(v * cosT[(row + r) * KD + d] + rot * sinT[(row + r) * KD + d]);
                }
            } else if (colg < 8192) {
                // V: write transposed directly — lane owns rows row..row+3 at col
                const int col = colg - 4096;
                const float bvv = bvp[col];
                bf16 tmp[4];
#pragma unroll
                for (int r = 0; r < 4; ++r)
                    tmp[r] = f2bf(acc[M][f][r] + bvv);
                *(uint2*)&vT[(size_t)col * TT + row] = *(const uint2*)tmp;
            } else {
                const int col = colg - 8192;
                const float bvv = bg[col];
#pragma unroll
                for (int r = 0; r < 4; ++r) {
                    float v = acc[M][f][r] + bvv;
                    sg[(size_t)(row + r) * VD + col] = f2bf(v / (1.f + __expf(-v)));
                }
            }
        }
    }
}

// ---------------------------------------------------------------------------
// Output GEMM, 8-phase 256x256 schedule, K-split x4 (K=1024 each, 16 K-tiles).
// Grid 256 = 1/CU. Partials written bf16 (halves traffic vs f32).
// ---------------------------------------------------------------------------
#define OSTA(bufs, u, k1) GLL(oA0 + (size_t)((u) * 64) * VD + (k1), sA + (bufs) + (u) * 4096 + tid * 8)
#define OSTB(bufs, u, k1) GLL(oB0 + (size_t)((u) * 64) * VD + (k1), sB + (bufs) + (u) * 4096 + tid * 8)

#define OLDA(dst, cb, qm) \
    _Pragma("unroll") for (int mi = 0; mi < 4; ++mi) { \
        const int r_ = wr * 128 + (qm) * 64 + mi * 16 + lr; \
        _Pragma("unroll") for (int ks = 0; ks < 2; ++ks) \
            dst[mi][ks] = *(const bf16x8*)&sA[(cb) + r_ * 64 + (((ks * 4 + g) ^ (lr & 7)) << 3)]; \
    }

#define OLDB(dst, cb, qn) \
    _Pragma("unroll") for (int ni = 0; ni < 2; ++ni) { \
        const int n_ = wcn * 64 + (qn) * 32 + ni * 16 + lr; \
        _Pragma("unroll") for (int ks = 0; ks < 2; ++ks) \
            dst[ni][ks] = *(const bf16x8*)&sB[(cb) + n_ * 64 + (((ks * 4 + g) ^ (lr & 7)) << 3)]; \
    }

#define OQ(qm, qn, RA, RB) __builtin_amdgcn_s_setprio(1); \
    _Pragma("unroll") for (int mi = 0; mi < 4; ++mi) \
        _Pragma("unroll") for (int ni = 0; ni < 2; ++ni) \
            _Pragma("unroll") for (int ks = 0; ks < 2; ++ks) \
                acc[(qm) * 4 + mi][(qn) * 2 + ni] = __builtin_amdgcn_mfma_f32_16x16x32_bf16( \
                    RA[mi][ks], RB[ni][ks], acc[(qm) * 4 + mi][(qn) * 2 + ni], 0, 0, 0); \
    __builtin_amdgcn_s_setprio(0);

__global__ __launch_bounds__(512, 2) void gemm_out_k(
    const bf16* __restrict__ Ag, const bf16* __restrict__ Bg,
    bf16* __restrict__ outp)
{
    __shared__ unsigned short sA[2 * 256 * 64];  // 64 KB
    __shared__ unsigned short sB[2 * 256 * 64];  // 64 KB
    constexpr int BUF1 = 16384;

    const int tid = threadIdx.x;
    const int lane = tid & 63;
    const int w = tid >> 6;
    const int wr = w >> 2;
    const int wcn = w & 3;
    const int lr = lane & 15;
    const int g = lane >> 4;

    const int flat = blockIdx.x;
    const int swz = (flat & 7) * 32 + (flat >> 3);
    const int z = swz >> 6;
    const int t64 = swz & 63;
    const int brow = (t64 & 7) * 256;
    const int bcol = (t64 >> 3) * 256;
    const int kbase = z * 1024;

    const bf16* oA0 = Ag + (size_t)(brow + (tid >> 3)) * VD + kbase + (((tid & 7) ^ ((tid >> 3) & 7)) << 3);
    const bf16* oB0 = Bg + (size_t)(bcol + (tid >> 3)) * VD + kbase + (((tid & 7) ^ ((tid >> 3) & 7)) << 3);

    f32x4 acc[8][4] = {};
    bf16x8 ra0[4][2], ra1[4][2], rb[2][2];

    OSTA(0, 0, 0); OSTA(0, 1, 0); OSTA(0, 2, 0); OSTA(0, 3, 0);
    OSTB(0, 0, 0); OSTB(0, 1, 0); OSTB(0, 2, 0); OSTB(0, 3, 0);
    OSTA(BUF1, 0, 64); OSTA(BUF1, 2, 64); OSTA(BUF1, 1, 64); OSTA(BUF1, 3, 64);
    OSTB(BUF1, 0, 64); OSTB(BUF1, 1, 64);
    WAIT6; MEMF; BAR;

    for (int I = 0; I < 7; ++I) {
        const int kB1 = I * 128 + 64;
        const int kN2 = I * 128 + 128;
        const int kN3 = I * 128 + 192;
        OLDA(ra0, 0, 0) OLDB(rb, 0, 0)
        OSTB(BUF1, 2, kB1); OSTB(BUF1, 3, kB1);
        MEMF; BAR; OQ(0, 0, ra0, rb) BAR;
        OLDA(ra1, 0, 1)
        OSTA(0, 0, kN2); OSTA(0, 2, kN2);
        MEMF; BAR; OQ(1, 0, ra1, rb) BAR;
        OLDB(rb, 0, 1)
        OSTA(0, 1, kN2); OSTA(0, 3, kN2);
        MEMF; BAR; OQ(1, 1, ra1, rb) BAR;
        OSTB(0, 0, kN2); OSTB(0, 1, kN2);
        WAIT6; MEMF; BAR; OQ(0, 1, ra0, rb) BAR;
        OLDA(ra0, BUF1, 0) OLDB(rb, BUF1, 0)
        OSTB(0, 2, kN2); OSTB(0, 3, kN2);
        MEMF; BAR; OQ(0, 0, ra0, rb) BAR;
        OLDA(ra1, BUF1, 1)
        OSTA(BUF1, 0, kN3); OSTA(BUF1, 2, kN3);
        MEMF; BAR; OQ(1, 0, ra1, rb) BAR;
        OLDB(rb, BUF1, 1)
        OSTA(BUF1, 1, kN3); OSTA(BUF1, 3, kN3);
        MEMF; BAR; OQ(1, 1, ra1, rb) BAR;
        OSTB(BUF1, 0, kN3); OSTB(BUF1, 1, kN3);
        WAIT6; MEMF; BAR; OQ(0, 1, ra0, rb) BAR;
    }
    {
        OLDA(ra0, 0, 0) OLDB(rb, 0, 0)
        OSTB(BUF1, 2, 960); OSTB(BUF1, 3, 960);
        MEMF; BAR; OQ(0, 0, ra0, rb) BAR;
        OLDA(ra1, 0, 1)
        MEMF; BAR; OQ(1, 0, ra1, rb) BAR;
        OLDB(rb, 0, 1)
        MEMF; BAR; OQ(1, 1, ra1, rb) BAR;
        WAIT0V; MEMF; BAR; OQ(0, 1, ra0, rb) BAR;
        OLDA(ra0, BUF1, 0) OLDB(rb, BUF1, 0)
        OQ(0, 0, ra0, rb)
        OLDA(ra1, BUF1, 1)
        OQ(1, 0, ra1, rb)
        OLDB(rb, BUF1, 1)
        OQ(1, 1, ra1, rb)
        OQ(0, 1, ra0, rb)
    }

    // epilogue: bf16 partial plane z
    bf16* op = outp + (size_t)z * TT * HD;
#pragma unroll
    for (int M = 0; M < 8; ++M) {
        const int row = brow + wr * 128 + (M >> 2) * 64 + (M & 3) * 16 + g * 4;
#pragma unroll
        for (int N = 0; N < 4; ++N) {
            const int col = bcol + wcn * 64 + (N >> 1) * 32 + (N & 1) * 16 + lr;
#pragma unroll
            for (int r = 0; r < 4; ++r)
                op[(size_t)(row + r) * HD + col] = f2bf(acc[M][N][r]);
        }
    }
}

// ---------------------------------------------------------------------------
// Combine 4 bf16 K-split partials + bias -> final f32 out
// ---------------------------------------------------------------------------
__global__ __launch_bounds__(256) void combine_out_k(const bf16* __restrict__ outp,
                                                     const float* __restrict__ bias,
                                                     float* __restrict__ out) {
    const size_t i = ((size_t)blockIdx.x * 256 + threadIdx.x) * 4;
    const size_t P = (size_t)TT * HD;
    unsigned short a[4], b[4], c[4], d[4];
    *(uint2*)a = *(const uint2*)(outp + i);
    *(uint2*)b = *(const uint2*)(outp + P + i);
    *(uint2*)c = *(const uint2*)(outp + 2 * P + i);
    *(uint2*)d = *(const uint2*)(outp + 3 * P + i);
    float4 bi = *(const float4*)(bias + (i & (HD - 1)));
    float o[4];
#pragma unroll
    for (int j = 0; j < 4; ++j)
        o[j] = (bf2f(a[j]) + bf2f(b[j])) + (bf2f(c[j]) + bf2f(d[j]));
    float4 ov = {o[0] + bi.x, o[1] + bi.y, o[2] + bi.z, o[3] + bi.w};
    *(float4*)(out + i) = ov;
}

// ---------------------------------------------------------------------------
// Fused causal retention + PV; factorized mask, dbuf P_lds (1 barrier/tile).
// Partials bf16. Grid: 1D 256 blocks, decoded so all 16 blocks of a head land
// on the SAME XCD (xcd = h&7) -> per-head K/V/Q stays L2-resident per XCD.
// ---------------------------------------------------------------------------
__global__ __launch_bounds__(512) void retention_fused_k(
    const bf16* __restrict__ qr, const bf16* __restrict__ kr,
    const bf16* __restrict__ vT,
    bf16* __restrict__ po0, bf16* __restrict__ po1,
    float* __restrict__ pr0, float* __restrict__ pr1)
{
    __shared__ unsigned short P_lds[2 * 128 * 128];  // 64 KB double-buffered
    __shared__ float rsum_lds[4][128];

    const int tid = threadIdx.x;
    const int lane = tid & 63;
    const int wid = tid >> 6;
    const int wr64 = (wid >> 2) * 64;
    const int wc = wid & 3;
    const int lr = lane & 15;
    const int g = lane >> 4;
    const int lk = g << 3;

    // XCD-locality decode: linear id % 8 == h % 8 (all same-head blocks on one XCD)
    const int flat = blockIdx.x;          // 0..255
    const int xcd = flat & 7;
    const int j = flat >> 3;              // 0..31
    const int h = xcd + 8 * (j & 1);      // heads {xcd, xcd+8}
    const int pidx = (j >> 1) & 7;        // 0..7
    const int parity = j >> 4;            // 0..1

    const float decay = logf(1.f - exp2f(-5.f - (float)h));
    bf16* __restrict__ po = parity ? po1 : po0;
    float* __restrict__ pr = parity ? pr1 : pr0;

    const int swzA = (lr & 7) << 3;

    const float bfac0 = __expf(decay * (float)(-(wc * 32 + lr)));
    const float bfac1 = __expf(decay * (float)(-(wc * 32 + 16 + lr)));
    const float astep = __expf(decay * -256.f);

    for (int sec = 0; sec < 2; ++sec) {
        const int qb = sec ? (15 - pidx) : pidx;
        const int qrow0 = qb * 128;

        bf16x8 af[4][4];
#pragma unroll
        for (int mi = 0; mi < 4; ++mi)
#pragma unroll
            for (int ks = 0; ks < 4; ++ks)
                af[mi][ks] = *(const bf16x8*)&qr[(size_t)(qrow0 + wr64 + mi * 16 + lr) * HD +
                                                 h * KD + ks * 32 + lk];

        f32x4 acc_o[4][4] = {};
        float rs[4][4] = {};
        float aexp[4][4];
#pragma unroll
        for (int mi = 0; mi < 4; ++mi)
#pragma unroll
            for (int r = 0; r < 4; ++r) {
                const int row_l = wr64 + mi * 16 + g * 4 + r;
                aexp[mi][r] = __expf(decay * (float)(qrow0 + row_l - parity * 128));
            }

        int pb = 0;
        for (int tb = parity; tb <= qb; tb += 2) {
            const int t0 = tb * 128;

            f32x4 acc_p[4][2] = {};
#pragma unroll
            for (int ks = 0; ks < 4; ++ks) {
                const bf16x8 b0 = *(const bf16x8*)&kr[(size_t)(t0 + wc * 32 + lr) * HD +
                                                      h * KD + ks * 32 + lk];
                const bf16x8 b1 = *(const bf16x8*)&kr[(size_t)(t0 + wc * 32 + 16 + lr) * HD +
                                                      h * KD + ks * 32 + lk];
#pragma unroll
                for (int mi = 0; mi < 4; ++mi) {
                    acc_p[mi][0] = __builtin_amdgcn_mfma_f32_16x16x32_bf16(af[mi][ks], b0, acc_p[mi][0], 0, 0, 0);
                    acc_p[mi][1] = __builtin_amdgcn_mfma_f32_16x16x32_bf16(af[mi][ks], b1, acc_p[mi][1], 0, 0, 0);
                }
            }

#pragma unroll
            for (int mi = 0; mi < 4; ++mi) {
#pragma unroll
                for (int r = 0; r < 4; ++r) {
                    const int rl = g * 4 + r;
                    const int row_l = wr64 + mi * 16 + rl;
                    const int srel = qrow0 + row_l - t0;
                    const float a = aexp[mi][r];
                    const float p0 = (wc * 32 + lr <= srel) ? acc_p[mi][0][r] * a * bfac0 : 0.f;
                    const float p1 = (wc * 32 + 16 + lr <= srel) ? acc_p[mi][1][r] * a * bfac1 : 0.f;
                    const int sw = (rl & 7) << 3;
                    P_lds[pb + row_l * 128 + ((wc * 32 + lr) ^ sw)] = f2bfu(p0);
                    P_lds[pb + row_l * 128 + ((wc * 32 + 16 + lr) ^ sw)] = f2bfu(p1);
                    rs[mi][r] += p0 + p1;
                    aexp[mi][r] = a * astep;
                }
            }
            __syncthreads();

#pragma unroll
            for (int ks2 = 0; ks2 < 4; ++ks2) {
                bf16x8 a2[4], b2[4];
#pragma unroll
                for (int mi = 0; mi < 4; ++mi)
                    a2[mi] = *(const bf16x8*)&P_lds[pb + (wr64 + mi * 16 + lr) * 128 +
                                                    ((ks2 * 32 + lk) ^ swzA)];
#pragma unroll
                for (int ni = 0; ni < 4; ++ni)
                    b2[ni] = *(const bf16x8*)&vT[(size_t)(h * DH + wc * 64 + ni * 16 + lr) * TT +
                                                 t0 + ks2 * 32 + lk];
#pragma unroll
                for (int mi = 0; mi < 4; ++mi)
#pragma unroll
                    for (int ni = 0; ni < 4; ++ni)
                        acc_o[mi][ni] = __builtin_amdgcn_mfma_f32_16x16x32_bf16(a2[mi], b2[ni], acc_o[mi][ni], 0, 0, 0);
            }
            pb ^= 16384;   // dbuf: next P-write targets the other buffer
        }

#pragma unroll
        for (int mi = 0; mi < 4; ++mi)
#pragma unroll
            for (int r = 0; r < 4; ++r) {
                float v = rs[mi][r];
                v += __shfl_xor(v, 1);
                v += __shfl_xor(v, 2);
                v += __shfl_xor(v, 4);
                v += __shfl_xor(v, 8);
                if (lr == 0) rsum_lds[wc][wr64 + mi * 16 + g * 4 + r] = v;
            }
        __syncthreads();
        if (tid < 128)
            pr[(size_t)h * TT + qrow0 + tid] =
                rsum_lds[0][tid] + rsum_lds[1][tid] + rsum_lds[2][tid] + rsum_lds[3][tid];

#pragma unroll
        for (int mi = 0; mi < 4; ++mi)
#pragma unroll
            for (int ni = 0; ni < 4; ++ni)
#pragma unroll
                for (int r = 0; r < 4; ++r) {
                    const int row_l = wr64 + mi * 16 + g * 4 + r;
                    const int col = wc * 64 + ni * 16 + lr;
                    po[(size_t)(qrow0 + row_l) * VD + h * DH + col] = f2bf(acc_o[mi][ni][r]);
                }
        __syncthreads();
    }
}

// ---------------------------------------------------------------------------
// Combine bf16 parity partials -> scale -> LN(256) -> silu-gate (bf16)
// ---------------------------------------------------------------------------
__global__ __launch_bounds__(256) void ln_gate_k(const bf16* __restrict__ po0,
                                                 const bf16* __restrict__ po1,
                                                 const float* __restrict__ pr0,
                                                 const float* __restrict__ pr1,
                                                 const bf16* __restrict__ sg,
                                                 bf16* __restrict__ gated) {
    const int tid = threadIdx.x;
    const int lane = tid & 63;
    const size_t ridx = (size_t)blockIdx.x * 4 + (tid >> 6);  // = s*16 + h
    const int h = (int)(ridx & 15);
    const int s = (int)(ridx >> 4);

    const float decay = logf(1.f - exp2f(-5.f - (float)h));
    const float Sm = -expm1f(decay * (float)(s + 1)) * exp2f(5.f + (float)h);
    const float norm = rsqrtf(Sm);
    const float raw = pr0[(size_t)h * TT + s] + pr1[(size_t)h * TT + s];
    const float scale = norm / fmaxf(1.f, fabsf(raw * norm));

    unsigned short ua[4], ub[4];
    *(uint2*)ua = *(const uint2*)(po0 + ridx * 256 + lane * 4);
    *(uint2*)ub = *(const uint2*)(po1 + ridx * 256 + lane * 4);
    float vv[4];
#pragma unroll
    for (int i = 0; i < 4; ++i)
        vv[i] = (bf2f(ua[i]) + bf2f(ub[i])) * scale;
    float sm = vv[0] + vv[1] + vv[2] + vv[3];
    float sq = vv[0] * vv[0] + vv[1] * vv[1] + vv[2] * vv[2] + vv[3] * vv[3];
#pragma unroll
    for (int o = 1; o < 64; o <<= 1) {
        sm += __shfl_xor(sm, o);
        sq += __shfl_xor(sq, o);
    }
    const float mu = sm * (1.f / 256.f);
    const float var = sq * (1.f / 256.f) - mu * mu;
    const float rstd = rsqrtf(var + 1e-6f);
    const bf16* sgp = sg + ridx * 256 + lane * 4;
    bf16* gp = gated + ridx * 256 + lane * 4;
    bf16 ob[4];
#pragma unroll
    for (int i = 0; i < 4; ++i)
        ob[i] = f2bf((vv[i] - mu) * rstd * __bfloat162float(sgp[i]));
    *(uint2*)gp = *(const uint2*)ob;
}

// ---------------------------------------------------------------------------
extern "C" void kernel_launch(void* const* d_in, const int* in_sizes, int n_in,
                              void* d_out, int out_size, void* d_ws, size_t ws_size,
                              hipStream_t stream) {
    const float* hidden = (const float*)d_in[0];
    const float* Wq = (const float*)d_in[1];
    const float* bq = (const float*)d_in[2];
    const float* Wk = (const float*)d_in[3];
    const float* bk = (const float*)d_in[4];
    const float* Wv = (const float*)d_in[5];
    const float* bvp = (const float*)d_in[6];
    const float* Wg = (const float*)d_in[7];
    const float* bg = (const float*)d_in[8];
    const float* Wo = (const float*)d_in[9];
    const float* bo = (const float*)d_in[10];
    const float* sinT = (const float*)d_in[11];
    const float* cosT = (const float*)d_in[12];
    float* out = (float*)d_out;

    char* p = (char*)d_ws;
    bf16* hb = (bf16*)p;    p += (size_t)TT * HD * 2;
    bf16* Wcat = (bf16*)p;  p += (size_t)(HD + HD + VD + VD) * HD * 2;
    bf16* WoT = (bf16*)p;   p += (size_t)HD * VD * 2;
    bf16* qr = (bf16*)p;    p += (size_t)TT * HD * 2;
    bf16* kr = (bf16*)p;    p += (size_t)TT * HD * 2;
    bf16* vT = (bf16*)p;    p += (size_t)VD * TT * 2;
    bf16* sg = (bf16*)p;    p += (size_t)TT * VD * 2;
    bf16* po0 = (bf16*)p;   p += (size_t)TT * VD * 2;
    bf16* po1 = (bf16*)p;   p += (size_t)TT * VD * 2;
    float* pr0 = (float*)p; p += (size_t)NH * TT * 4;
    float* pr1 = (float*)p; p += (size_t)NH * TT * 4;
    bf16* gated = (bf16*)p; p += (size_t)TT * VD * 2;
    bf16* outp = (bf16*)p;  p += (size_t)4 * TT * HD * 2;

    // 1) weight transposes + hidden convert (single launch)
    transpose_all_k<<<8704, 256, 0, stream>>>(Wq, Wk, Wv, Wg, Wo, Wcat, WoT, hidden, hb);

    // 2) fused QKVG projection (8-phase 256x192); V written transposed in-epilogue
    gemm_qkvg_k<<<512, 512, 0, stream>>>(hb, Wcat, bq, bk, bvp, bg, sinT, cosT,
                                         qr, kr, vT, sg);

    // 3) fused causal retention + PV (XCD-local head mapping)
    retention_fused_k<<<256, 512, 0, stream>>>(qr, kr, vT, po0, po1, pr0, pr1);

    // 4) combine + groupnorm + gate, then output projection (8-phase, K-split x4)
    ln_gate_k<<<TT * NH / 4, 256, 0, stream>>>(po0, po1, pr0, pr1, sg, gated);
    gemm_out_k<<<256, 512, 0, stream>>>(gated, WoT, outp);
    combine_out_k<<<TT * HD / 1024, 256, 0, stream>>>(outp, bo, out);
}

// Round 17
// 305.582 us; speedup vs baseline: 1.0654x; 1.0654x over previous
//
#include <hip/hip_runtime.h>
#include <hip/hip_bf16.h>

typedef __hip_bfloat16 bf16;
typedef __attribute__((ext_vector_type(8))) __bf16 bf16x8;
typedef __attribute__((ext_vector_type(4))) float f32x4;

constexpr int TT = 2048;   // sequence length
constexpr int HD = 2048;   // hidden dim
constexpr int VD = 4096;   // value dim
constexpr int KD = 128;    // key dim per head
constexpr int NH = 16;     // heads
constexpr int DH = 256;    // head dim of v
constexpr float K_SCALING = 0.08838834764831845f;  // 128^-0.5

__device__ __forceinline__ bf16 f2bf(float x) { return __float2bfloat16(x); }
__device__ __forceinline__ unsigned short f2bfu(float x) {
    bf16 b = __float2bfloat16(x);
    return *reinterpret_cast<unsigned short*>(&b);
}
__device__ __forceinline__ float bf2f(unsigned short u) {
    unsigned int x = ((unsigned int)u) << 16;
    return __uint_as_float(x);
}

// ---------------------------------------------------------------------------
// Batched: all 5 weight transposes (8192 tiles) + hidden f32->bf16 (512 blocks)
// ---------------------------------------------------------------------------
__global__ __launch_bounds__(256) void transpose_all_k(
    const float* __restrict__ Wq, const float* __restrict__ Wk,
    const float* __restrict__ Wv, const float* __restrict__ Wg,
    const float* __restrict__ Wo, bf16* __restrict__ Wcat, bf16* __restrict__ WoT,
    const float* __restrict__ hidden, bf16* __restrict__ hb)
{
    __shared__ unsigned short sT[64 * 72];
    int t2 = blockIdx.x;
    if (t2 >= 8192) {
        const int b = t2 - 8192;
        const size_t base = (size_t)b * 8192;
#pragma unroll
        for (int j = 0; j < 8; ++j) {
            const size_t i = base + j * 1024 + threadIdx.x * 4;
            float4 v = *(const float4*)(hidden + i);
            bf16 tmp[4] = {f2bf(v.x), f2bf(v.y), f2bf(v.z), f2bf(v.w)};
            *(uint2*)(hb + i) = *(const uint2*)tmp;
        }
        return;
    }
    const float* src;
    bf16* dst;
    int R, C;
    if (t2 < 1024)      { src = Wq; dst = Wcat;                     R = 2048; C = 2048; }
    else if (t2 < 2048) { src = Wk; dst = Wcat + (size_t)2048 * HD; R = 2048; C = 2048; t2 -= 1024; }
    else if (t2 < 4096) { src = Wv; dst = Wcat + (size_t)4096 * HD; R = 2048; C = 4096; t2 -= 2048; }
    else if (t2 < 6144) { src = Wg; dst = Wcat + (size_t)8192 * HD; R = 2048; C = 4096; t2 -= 4096; }
    else                { src = Wo; dst = WoT;                      R = 4096; C = 2048; t2 -= 6144; }
    const int xt = C >> 6;
    const int x0 = (t2 % xt) * 64;
    const int y0 = (t2 / xt) * 64;

    const int t = threadIdx.x;
    {
        const int r = t >> 2;
        const int c0 = (t & 3) << 4;
        const float* s = src + (size_t)(y0 + r) * C + x0 + c0;
        unsigned short e[16];
#pragma unroll
        for (int j = 0; j < 4; ++j) {
            float4 v = *(const float4*)(s + j * 4);
            e[j * 4 + 0] = f2bfu(v.x);
            e[j * 4 + 1] = f2bfu(v.y);
            e[j * 4 + 2] = f2bfu(v.z);
            e[j * 4 + 3] = f2bfu(v.w);
        }
#pragma unroll
        for (int i = 0; i < 16; ++i) {
            const int c = c0 + i;
            sT[c * 72 + (r ^ (((c >> 3) & 7) << 3))] = e[i];
        }
    }
    __syncthreads();
    {
        const int c = t >> 2;
        const int r0 = (t & 3) << 4;
        const int xs = ((c >> 3) & 7) << 3;
#pragma unroll
        for (int s2 = 0; s2 < 16; s2 += 8) {
            bf16x8 v = *(const bf16x8*)&sT[c * 72 + ((r0 + s2) ^ xs)];
            *(bf16x8*)&dst[(size_t)(x0 + c) * R + y0 + r0 + s2] = v;
        }
    }
}

// ---------------------------------------------------------------------------
// Fused QKVG GEMM, 8-phase 256x192 schedule (BK=64, 2 K-tiles/iter).
// V segment written TRANSPOSED directly to vT (per-lane 8B stores).
// ---------------------------------------------------------------------------
#define GLL(gptr, lptr) __builtin_amdgcn_global_load_lds( \
    (const __attribute__((address_space(1))) void*)(gptr), \
    (__attribute__((address_space(3))) void*)(lptr), 16, 0, 0)

#define STA(bufs, u, k1) GLL(gA0 + (size_t)((u) * 64) * HD + (k1), sA + (bufs) + (u) * 4096 + tid * 8)
#define STB(bufs, u, k1) GLL(gB0 + (size_t)((u) * 64) * HD + (k1), sB + (bufs) + (u) * 4096 + tid * 8)

#define WAIT6 asm volatile("s_waitcnt vmcnt(6)" ::: "memory")
#define WAIT0V asm volatile("s_waitcnt vmcnt(0)" ::: "memory")
#define MEMF asm volatile("" ::: "memory")
#define BAR __builtin_amdgcn_s_barrier()

#define LDA(dst, cb, qm) \
    _Pragma("unroll") for (int mi = 0; mi < 4; ++mi) { \
        const int r_ = wr * 128 + (qm) * 64 + mi * 16 + lr; \
        _Pragma("unroll") for (int ks = 0; ks < 2; ++ks) \
            dst[mi][ks] = *(const bf16x8*)&sA[(cb) + r_ * 64 + (((ks * 4 + g) ^ (lr & 7)) << 3)]; \
    }

#define LDB01(dst, cb) \
    _Pragma("unroll") for (int ni = 0; ni < 2; ++ni) { \
        const int n_ = wcn * 48 + ni * 16 + lr; \
        _Pragma("unroll") for (int ks = 0; ks < 2; ++ks) \
            dst[ni][ks] = *(const bf16x8*)&sB[(cb) + n_ * 64 + (((ks * 4 + g) ^ (lr & 7)) << 3)]; \
    }

#define LDB2(dst, cb) { \
        const int n_ = wcn * 48 + 32 + lr; \
        _Pragma("unroll") for (int ks = 0; ks < 2; ++ks) \
            dst[ks] = *(const bf16x8*)&sB[(cb) + n_ * 64 + (((ks * 4 + g) ^ (lr & 7)) << 3)]; \
    }

#define Q00 __builtin_amdgcn_s_setprio(1); \
    _Pragma("unroll") for (int mi = 0; mi < 4; ++mi) \
        _Pragma("unroll") for (int ni = 0; ni < 2; ++ni) \
            _Pragma("unroll") for (int ks = 0; ks < 2; ++ks) \
                acc[mi][ni] = __builtin_amdgcn_mfma_f32_16x16x32_bf16(ra0[mi][ks], rb[ni][ks], acc[mi][ni], 0, 0, 0); \
    __builtin_amdgcn_s_setprio(0);
#define Q10 __builtin_amdgcn_s_setprio(1); \
    _Pragma("unroll") for (int mi = 0; mi < 4; ++mi) \
        _Pragma("unroll") for (int ni = 0; ni < 2; ++ni) \
            _Pragma("unroll") for (int ks = 0; ks < 2; ++ks) \
                acc[4 + mi][ni] = __builtin_amdgcn_mfma_f32_16x16x32_bf16(ra1[mi][ks], rb[ni][ks], acc[4 + mi][ni], 0, 0, 0); \
    __builtin_amdgcn_s_setprio(0);
#define Q11 __builtin_amdgcn_s_setprio(1); \
    _Pragma("unroll") for (int mi = 0; mi < 4; ++mi) \
        _Pragma("unroll") for (int ks = 0; ks < 2; ++ks) \
            acc[4 + mi][2] = __builtin_amdgcn_mfma_f32_16x16x32_bf16(ra1[mi][ks], rb2[ks], acc[4 + mi][2], 0, 0, 0); \
    __builtin_amdgcn_s_setprio(0);
#define Q01 __builtin_amdgcn_s_setprio(1); \
    _Pragma("unroll") for (int mi = 0; mi < 4; ++mi) \
        _Pragma("unroll") for (int ks = 0; ks < 2; ++ks) \
            acc[mi][2] = __builtin_amdgcn_mfma_f32_16x16x32_bf16(ra0[mi][ks], rb2[ks], acc[mi][2], 0, 0, 0); \
    __builtin_amdgcn_s_setprio(0);

__global__ __launch_bounds__(512, 2) void gemm_qkvg_k(
    const bf16* __restrict__ Ag, const bf16* __restrict__ Bg,
    const float* __restrict__ bq, const float* __restrict__ bk,
    const float* __restrict__ bvp, const float* __restrict__ bg,
    const float* __restrict__ sinT, const float* __restrict__ cosT,
    bf16* __restrict__ qr, bf16* __restrict__ kr,
    bf16* __restrict__ vT, bf16* __restrict__ sg)
{
    __shared__ unsigned short sA[2 * 256 * 64];
    __shared__ unsigned short sB[2 * 192 * 64];
    constexpr int BUFA = 16384, BUFB = 12288;

    const int tid = threadIdx.x;
    const int lane = tid & 63;
    const int w = tid >> 6;
    const int wr = w >> 2;
    const int wcn = w & 3;
    const int lr = lane & 15;
    const int g = lane >> 4;

    const int flat = blockIdx.x;
    const int swz = (flat & 7) * 64 + (flat >> 3);
    const int brow = (swz & 7) * 256;
    const int bcol = (swz >> 3) * 192;

    const bf16* gA0 = Ag + (size_t)(brow + (tid >> 3)) * HD + (((tid & 7) ^ ((tid >> 3) & 7)) << 3);
    const bf16* gB0 = Bg + (size_t)(bcol + (tid >> 3)) * HD + (((tid & 7) ^ ((tid >> 3) & 7)) << 3);

    f32x4 acc[8][3] = {};
    bf16x8 ra0[4][2], ra1[4][2], rb[2][2], rb2[2];

    STA(0, 0, 0); STA(0, 1, 0); STA(0, 2, 0); STA(0, 3, 0);
    STB(0, 0, 0); STB(0, 1, 0); STB(0, 2, 0);
    STA(BUFA, 0, 64); STA(BUFA, 1, 64); STA(BUFA, 2, 64); STA(BUFA, 3, 64);
    STB(BUFB, 0, 64); STB(BUFB, 1, 64);
    WAIT6; MEMF; BAR;

    for (int I = 0; I < 15; ++I) {
        const int kB1 = I * 128 + 64;
        const int kN2 = I * 128 + 128;
        const int kN3 = I * 128 + 192;
        LDA(ra0, 0, 0) LDB01(rb, 0)
        STB(BUFB, 2, kB1);
        MEMF; BAR; Q00 BAR;
        LDA(ra1, 0, 1)
        STA(0, 0, kN2); STA(0, 2, kN2);
        MEMF; BAR; Q10 BAR;
        LDB2(rb2, 0)
        STA(0, 1, kN2); STA(0, 3, kN2);
        MEMF; BAR; Q11 BAR;
        STB(0, 0, kN2); STB(0, 1, kN2);
        WAIT6; MEMF; BAR; Q01 BAR;
        LDA(ra0, BUFA, 0) LDB01(rb, BUFB)
        STB(0, 2, kN2);
        MEMF; BAR; Q00 BAR;
        LDA(ra1, BUFA, 1)
        STA(BUFA, 0, kN3); STA(BUFA, 2, kN3);
        MEMF; BAR; Q10 BAR;
        LDB2(rb2, BUFB)
        STA(BUFA, 1, kN3); STA(BUFA, 3, kN3);
        MEMF; BAR; Q11 BAR;
        STB(BUFB, 0, kN3); STB(BUFB, 1, kN3);
        WAIT6; MEMF; BAR; Q01 BAR;
    }
    {
        LDA(ra0, 0, 0) LDB01(rb, 0)
        STB(BUFB, 2, 1984);
        MEMF; BAR; Q00 BAR;
        LDA(ra1, 0, 1)
        MEMF; BAR; Q10 BAR;
        LDB2(rb2, 0)
        MEMF; BAR; Q11 BAR;
        WAIT0V; MEMF; BAR; Q01 BAR;
        LDA(ra0, BUFA, 0) LDB01(rb, BUFB)
        Q00
        LDA(ra1, BUFA, 1)
        Q10
        LDB2(rb2, BUFB)
        Q11
        Q01
    }

#pragma unroll
    for (int M = 0; M < 8; ++M) {
        const int row = brow + wr * 128 + (M >> 2) * 64 + (M & 3) * 16 + g * 4;
#pragma unroll
        for (int f = 0; f < 3; ++f) {
            const int colg = bcol + wcn * 48 + f * 16 + lr;
            if (colg < 4096) {
                const bool isK = (colg >= 2048);
                const int col = colg - (isK ? 2048 : 0);
                const float bvv = (isK ? bk : bq)[col];
                const float scale = isK ? K_SCALING : 1.f;
                bf16* outb = isK ? kr : qr;
                const int d = col & (KD - 1);
#pragma unroll
                for (int r = 0; r < 4; ++r) {
                    float v = (acc[M][f][r] + bvv) * scale;
                    float o = __shfl_xor(v, 1);
                    float rot = (col & 1) ? o : -o;
                    outb[(size_t)(row + r) * HD + col] =
                        f2bf(v * cosT[(row + r) * KD + d] + rot * sinT[(row + r) * KD + d]);
                }
            } else if (colg < 8192) {
                // V: write transposed directly — lane owns rows row..row+3 at col
                const int col = colg - 4096;
                const float bvv = bvp[col];
                bf16 tmp[4];
#pragma unroll
                for (int r = 0; r < 4; ++r)
                    tmp[r] = f2bf(acc[M][f][r] + bvv);
                *(uint2*)&vT[(size_t)col * TT + row] = *(const uint2*)tmp;
            } else {
                const int col = colg - 8192;
                const float bvv = bg[col];
#pragma unroll
                for (int r = 0; r < 4; ++r) {
                    float v = acc[M][f][r] + bvv;
                    sg[(size_t)(row + r) * VD + col] = f2bf(v / (1.f + __expf(-v)));
                }
            }
        }
    }
}

// ---------------------------------------------------------------------------
// Output GEMM, 8-phase 256x256 schedule, K-split x4 (K=1024 each, 16 K-tiles).
// Grid 256 = 1/CU. Partials written bf16 (halves traffic vs f32).
// ---------------------------------------------------------------------------
#define OSTA(bufs, u, k1) GLL(oA0 + (size_t)((u) * 64) * VD + (k1), sA + (bufs) + (u) * 4096 + tid * 8)
#define OSTB(bufs, u, k1) GLL(oB0 + (size_t)((u) * 64) * VD + (k1), sB + (bufs) + (u) * 4096 + tid * 8)

#define OLDA(dst, cb, qm) \
    _Pragma("unroll") for (int mi = 0; mi < 4; ++mi) { \
        const int r_ = wr * 128 + (qm) * 64 + mi * 16 + lr; \
        _Pragma("unroll") for (int ks = 0; ks < 2; ++ks) \
            dst[mi][ks] = *(const bf16x8*)&sA[(cb) + r_ * 64 + (((ks * 4 + g) ^ (lr & 7)) << 3)]; \
    }

#define OLDB(dst, cb, qn) \
    _Pragma("unroll") for (int ni = 0; ni < 2; ++ni) { \
        const int n_ = wcn * 64 + (qn) * 32 + ni * 16 + lr; \
        _Pragma("unroll") for (int ks = 0; ks < 2; ++ks) \
            dst[ni][ks] = *(const bf16x8*)&sB[(cb) + n_ * 64 + (((ks * 4 + g) ^ (lr & 7)) << 3)]; \
    }

#define OQ(qm, qn, RA, RB) __builtin_amdgcn_s_setprio(1); \
    _Pragma("unroll") for (int mi = 0; mi < 4; ++mi) \
        _Pragma("unroll") for (int ni = 0; ni < 2; ++ni) \
            _Pragma("unroll") for (int ks = 0; ks < 2; ++ks) \
                acc[(qm) * 4 + mi][(qn) * 2 + ni] = __builtin_amdgcn_mfma_f32_16x16x32_bf16( \
                    RA[mi][ks], RB[ni][ks], acc[(qm) * 4 + mi][(qn) * 2 + ni], 0, 0, 0); \
    __builtin_amdgcn_s_setprio(0);

__global__ __launch_bounds__(512, 2) void gemm_out_k(
    const bf16* __restrict__ Ag, const bf16* __restrict__ Bg,
    bf16* __restrict__ outp)
{
    __shared__ unsigned short sA[2 * 256 * 64];  // 64 KB
    __shared__ unsigned short sB[2 * 256 * 64];  // 64 KB
    constexpr int BUF1 = 16384;

    const int tid = threadIdx.x;
    const int lane = tid & 63;
    const int w = tid >> 6;
    const int wr = w >> 2;
    const int wcn = w & 3;
    const int lr = lane & 15;
    const int g = lane >> 4;

    const int flat = blockIdx.x;
    const int swz = (flat & 7) * 32 + (flat >> 3);
    const int z = swz >> 6;
    const int t64 = swz & 63;
    const int brow = (t64 & 7) * 256;
    const int bcol = (t64 >> 3) * 256;
    const int kbase = z * 1024;

    const bf16* oA0 = Ag + (size_t)(brow + (tid >> 3)) * VD + kbase + (((tid & 7) ^ ((tid >> 3) & 7)) << 3);
    const bf16* oB0 = Bg + (size_t)(bcol + (tid >> 3)) * VD + kbase + (((tid & 7) ^ ((tid >> 3) & 7)) << 3);

    f32x4 acc[8][4] = {};
    bf16x8 ra0[4][2], ra1[4][2], rb[2][2];

    OSTA(0, 0, 0); OSTA(0, 1, 0); OSTA(0, 2, 0); OSTA(0, 3, 0);
    OSTB(0, 0, 0); OSTB(0, 1, 0); OSTB(0, 2, 0); OSTB(0, 3, 0);
    OSTA(BUF1, 0, 64); OSTA(BUF1, 2, 64); OSTA(BUF1, 1, 64); OSTA(BUF1, 3, 64);
    OSTB(BUF1, 0, 64); OSTB(BUF1, 1, 64);
    WAIT6; MEMF; BAR;

    for (int I = 0; I < 7; ++I) {
        const int kB1 = I * 128 + 64;
        const int kN2 = I * 128 + 128;
        const int kN3 = I * 128 + 192;
        OLDA(ra0, 0, 0) OLDB(rb, 0, 0)
        OSTB(BUF1, 2, kB1); OSTB(BUF1, 3, kB1);
        MEMF; BAR; OQ(0, 0, ra0, rb) BAR;
        OLDA(ra1, 0, 1)
        OSTA(0, 0, kN2); OSTA(0, 2, kN2);
        MEMF; BAR; OQ(1, 0, ra1, rb) BAR;
        OLDB(rb, 0, 1)
        OSTA(0, 1, kN2); OSTA(0, 3, kN2);
        MEMF; BAR; OQ(1, 1, ra1, rb) BAR;
        OSTB(0, 0, kN2); OSTB(0, 1, kN2);
        WAIT6; MEMF; BAR; OQ(0, 1, ra0, rb) BAR;
        OLDA(ra0, BUF1, 0) OLDB(rb, BUF1, 0)
        OSTB(0, 2, kN2); OSTB(0, 3, kN2);
        MEMF; BAR; OQ(0, 0, ra0, rb) BAR;
        OLDA(ra1, BUF1, 1)
        OSTA(BUF1, 0, kN3); OSTA(BUF1, 2, kN3);
        MEMF; BAR; OQ(1, 0, ra1, rb) BAR;
        OLDB(rb, BUF1, 1)
        OSTA(BUF1, 1, kN3); OSTA(BUF1, 3, kN3);
        MEMF; BAR; OQ(1, 1, ra1, rb) BAR;
        OSTB(BUF1, 0, kN3); OSTB(BUF1, 1, kN3);
        WAIT6; MEMF; BAR; OQ(0, 1, ra0, rb) BAR;
    }
    {
        OLDA(ra0, 0, 0) OLDB(rb, 0, 0)
        OSTB(BUF1, 2, 960); OSTB(BUF1, 3, 960);
        MEMF; BAR; OQ(0, 0, ra0, rb) BAR;
        OLDA(ra1, 0, 1)
        MEMF; BAR; OQ(1, 0, ra1, rb) BAR;
        OLDB(rb, 0, 1)
        MEMF; BAR; OQ(1, 1, ra1, rb) BAR;
        WAIT0V; MEMF; BAR; OQ(0, 1, ra0, rb) BAR;
        OLDA(ra0, BUF1, 0) OLDB(rb, BUF1, 0)
        OQ(0, 0, ra0, rb)
        OLDA(ra1, BUF1, 1)
        OQ(1, 0, ra1, rb)
        OLDB(rb, BUF1, 1)
        OQ(1, 1, ra1, rb)
        OQ(0, 1, ra0, rb)
    }

    // epilogue: bf16 partial plane z
    bf16* op = outp + (size_t)z * TT * HD;
#pragma unroll
    for (int M = 0; M < 8; ++M) {
        const int row = brow + wr * 128 + (M >> 2) * 64 + (M & 3) * 16 + g * 4;
#pragma unroll
        for (int N = 0; N < 4; ++N) {
            const int col = bcol + wcn * 64 + (N >> 1) * 32 + (N & 1) * 16 + lr;
#pragma unroll
            for (int r = 0; r < 4; ++r)
                op[(size_t)(row + r) * HD + col] = f2bf(acc[M][N][r]);
        }
    }
}

// ---------------------------------------------------------------------------
// Combine 4 bf16 K-split partials + bias -> final f32 out
// ---------------------------------------------------------------------------
__global__ __launch_bounds__(256) void combine_out_k(const bf16* __restrict__ outp,
                                                     const float* __restrict__ bias,
                                                     float* __restrict__ out) {
    const size_t i = ((size_t)blockIdx.x * 256 + threadIdx.x) * 4;
    const size_t P = (size_t)TT * HD;
    unsigned short a[4], b[4], c[4], d[4];
    *(uint2*)a = *(const uint2*)(outp + i);
    *(uint2*)b = *(const uint2*)(outp + P + i);
    *(uint2*)c = *(const uint2*)(outp + 2 * P + i);
    *(uint2*)d = *(const uint2*)(outp + 3 * P + i);
    float4 bi = *(const float4*)(bias + (i & (HD - 1)));
    float o[4];
#pragma unroll
    for (int j = 0; j < 4; ++j)
        o[j] = (bf2f(a[j]) + bf2f(b[j])) + (bf2f(c[j]) + bf2f(d[j]));
    float4 ov = {o[0] + bi.x, o[1] + bi.y, o[2] + bi.z, o[3] + bi.w};
    *(float4*)(out + i) = ov;
}

// ---------------------------------------------------------------------------
// Fused causal retention + PV; factorized mask, dbuf P_lds (1 barrier/tile).
// Partials bf16. Grid: (8, 2, 16) = 256 blocks x 512 threads.
// (Round-15 proven version: default grid decode.)
// ---------------------------------------------------------------------------
__global__ __launch_bounds__(512) void retention_fused_k(
    const bf16* __restrict__ qr, const bf16* __restrict__ kr,
    const bf16* __restrict__ vT,
    bf16* __restrict__ po0, bf16* __restrict__ po1,
    float* __restrict__ pr0, float* __restrict__ pr1)
{
    __shared__ unsigned short P_lds[2 * 128 * 128];  // 64 KB double-buffered
    __shared__ float rsum_lds[4][128];

    const int tid = threadIdx.x;
    const int lane = tid & 63;
    const int wid = tid >> 6;
    const int wr64 = (wid >> 2) * 64;
    const int wc = wid & 3;
    const int lr = lane & 15;
    const int g = lane >> 4;
    const int lk = g << 3;
    const int pidx = blockIdx.x;
    const int parity = blockIdx.y;
    const int h = blockIdx.z;

    const float decay = logf(1.f - exp2f(-5.f - (float)h));
    bf16* __restrict__ po = parity ? po1 : po0;
    float* __restrict__ pr = parity ? pr1 : pr0;

    const int swzA = (lr & 7) << 3;

    const float bfac0 = __expf(decay * (float)(-(wc * 32 + lr)));
    const float bfac1 = __expf(decay * (float)(-(wc * 32 + 16 + lr)));
    const float astep = __expf(decay * -256.f);

    for (int sec = 0; sec < 2; ++sec) {
        const int qb = sec ? (15 - pidx) : pidx;
        const int qrow0 = qb * 128;

        bf16x8 af[4][4];
#pragma unroll
        for (int mi = 0; mi < 4; ++mi)
#pragma unroll
            for (int ks = 0; ks < 4; ++ks)
                af[mi][ks] = *(const bf16x8*)&qr[(size_t)(qrow0 + wr64 + mi * 16 + lr) * HD +
                                                 h * KD + ks * 32 + lk];

        f32x4 acc_o[4][4] = {};
        float rs[4][4] = {};
        float aexp[4][4];
#pragma unroll
        for (int mi = 0; mi < 4; ++mi)
#pragma unroll
            for (int r = 0; r < 4; ++r) {
                const int row_l = wr64 + mi * 16 + g * 4 + r;
                aexp[mi][r] = __expf(decay * (float)(qrow0 + row_l - parity * 128));
            }

        int pb = 0;
        for (int tb = parity; tb <= qb; tb += 2) {
            const int t0 = tb * 128;

            f32x4 acc_p[4][2] = {};
#pragma unroll
            for (int ks = 0; ks < 4; ++ks) {
                const bf16x8 b0 = *(const bf16x8*)&kr[(size_t)(t0 + wc * 32 + lr) * HD +
                                                      h * KD + ks * 32 + lk];
                const bf16x8 b1 = *(const bf16x8*)&kr[(size_t)(t0 + wc * 32 + 16 + lr) * HD +
                                                      h * KD + ks * 32 + lk];
#pragma unroll
                for (int mi = 0; mi < 4; ++mi) {
                    acc_p[mi][0] = __builtin_amdgcn_mfma_f32_16x16x32_bf16(af[mi][ks], b0, acc_p[mi][0], 0, 0, 0);
                    acc_p[mi][1] = __builtin_amdgcn_mfma_f32_16x16x32_bf16(af[mi][ks], b1, acc_p[mi][1], 0, 0, 0);
                }
            }

#pragma unroll
            for (int mi = 0; mi < 4; ++mi) {
#pragma unroll
                for (int r = 0; r < 4; ++r) {
                    const int rl = g * 4 + r;
                    const int row_l = wr64 + mi * 16 + rl;
                    const int srel = qrow0 + row_l - t0;
                    const float a = aexp[mi][r];
                    const float p0 = (wc * 32 + lr <= srel) ? acc_p[mi][0][r] * a * bfac0 : 0.f;
                    const float p1 = (wc * 32 + 16 + lr <= srel) ? acc_p[mi][1][r] * a * bfac1 : 0.f;
                    const int sw = (rl & 7) << 3;
                    P_lds[pb + row_l * 128 + ((wc * 32 + lr) ^ sw)] = f2bfu(p0);
                    P_lds[pb + row_l * 128 + ((wc * 32 + 16 + lr) ^ sw)] = f2bfu(p1);
                    rs[mi][r] += p0 + p1;
                    aexp[mi][r] = a * astep;
                }
            }
            __syncthreads();

#pragma unroll
            for (int ks2 = 0; ks2 < 4; ++ks2) {
                bf16x8 a2[4], b2[4];
#pragma unroll
                for (int mi = 0; mi < 4; ++mi)
                    a2[mi] = *(const bf16x8*)&P_lds[pb + (wr64 + mi * 16 + lr) * 128 +
                                                    ((ks2 * 32 + lk) ^ swzA)];
#pragma unroll
                for (int ni = 0; ni < 4; ++ni)
                    b2[ni] = *(const bf16x8*)&vT[(size_t)(h * DH + wc * 64 + ni * 16 + lr) * TT +
                                                 t0 + ks2 * 32 + lk];
#pragma unroll
                for (int mi = 0; mi < 4; ++mi)
#pragma unroll
                    for (int ni = 0; ni < 4; ++ni)
                        acc_o[mi][ni] = __builtin_amdgcn_mfma_f32_16x16x32_bf16(a2[mi], b2[ni], acc_o[mi][ni], 0, 0, 0);
            }
            pb ^= 16384;   // dbuf: next P-write targets the other buffer
        }

#pragma unroll
        for (int mi = 0; mi < 4; ++mi)
#pragma unroll
            for (int r = 0; r < 4; ++r) {
                float v = rs[mi][r];
                v += __shfl_xor(v, 1);
                v += __shfl_xor(v, 2);
                v += __shfl_xor(v, 4);
                v += __shfl_xor(v, 8);
                if (lr == 0) rsum_lds[wc][wr64 + mi * 16 + g * 4 + r] = v;
            }
        __syncthreads();
        if (tid < 128)
            pr[(size_t)h * TT + qrow0 + tid] =
                rsum_lds[0][tid] + rsum_lds[1][tid] + rsum_lds[2][tid] + rsum_lds[3][tid];

#pragma unroll
        for (int mi = 0; mi < 4; ++mi)
#pragma unroll
            for (int ni = 0; ni < 4; ++ni)
#pragma unroll
                for (int r = 0; r < 4; ++r) {
                    const int row_l = wr64 + mi * 16 + g * 4 + r;
                    const int col = wc * 64 + ni * 16 + lr;
                    po[(size_t)(qrow0 + row_l) * VD + h * DH + col] = f2bf(acc_o[mi][ni][r]);
                }
        __syncthreads();
    }
}

// ---------------------------------------------------------------------------
// Combine bf16 parity partials -> scale -> LN(256) -> silu-gate (bf16)
// ---------------------------------------------------------------------------
__global__ __launch_bounds__(256) void ln_gate_k(const bf16* __restrict__ po0,
                                                 const bf16* __restrict__ po1,
                                                 const float* __restrict__ pr0,
                                                 const float* __restrict__ pr1,
                                                 const bf16* __restrict__ sg,
                                                 bf16* __restrict__ gated) {
    const int tid = threadIdx.x;
    const int lane = tid & 63;
    const size_t ridx = (size_t)blockIdx.x * 4 + (tid >> 6);  // = s*16 + h
    const int h = (int)(ridx & 15);
    const int s = (int)(ridx >> 4);

    const float decay = logf(1.f - exp2f(-5.f - (float)h));
    const float Sm = -expm1f(decay * (float)(s + 1)) * exp2f(5.f + (float)h);
    const float norm = rsqrtf(Sm);
    const float raw = pr0[(size_t)h * TT + s] + pr1[(size_t)h * TT + s];
    const float scale = norm / fmaxf(1.f, fabsf(raw * norm));

    unsigned short ua[4], ub[4];
    *(uint2*)ua = *(const uint2*)(po0 + ridx * 256 + lane * 4);
    *(uint2*)ub = *(const uint2*)(po1 + ridx * 256 + lane * 4);
    float vv[4];
#pragma unroll
    for (int i = 0; i < 4; ++i)
        vv[i] = (bf2f(ua[i]) + bf2f(ub[i])) * scale;
    float sm = vv[0] + vv[1] + vv[2] + vv[3];
    float sq = vv[0] * vv[0] + vv[1] * vv[1] + vv[2] * vv[2] + vv[3] * vv[3];
#pragma unroll
    for (int o = 1; o < 64; o <<= 1) {
        sm += __shfl_xor(sm, o);
        sq += __shfl_xor(sq, o);
    }
    const float mu = sm * (1.f / 256.f);
    const float var = sq * (1.f / 256.f) - mu * mu;
    const float rstd = rsqrtf(var + 1e-6f);
    const bf16* sgp = sg + ridx * 256 + lane * 4;
    bf16* gp = gated + ridx * 256 + lane * 4;
    bf16 ob[4];
#pragma unroll
    for (int i = 0; i < 4; ++i)
        ob[i] = f2bf((vv[i] - mu) * rstd * __bfloat162float(sgp[i]));
    *(uint2*)gp = *(const uint2*)ob;
}

// ---------------------------------------------------------------------------
extern "C" void kernel_launch(void* const* d_in, const int* in_sizes, int n_in,
                              void* d_out, int out_size, void* d_ws, size_t ws_size,
                              hipStream_t stream) {
    const float* hidden = (const float*)d_in[0];
    const float* Wq = (const float*)d_in[1];
    const float* bq = (const float*)d_in[2];
    const float* Wk = (const float*)d_in[3];
    const float* bk = (const float*)d_in[4];
    const float* Wv = (const float*)d_in[5];
    const float* bvp = (const float*)d_in[6];
    const float* Wg = (const float*)d_in[7];
    const float* bg = (const float*)d_in[8];
    const float* Wo = (const float*)d_in[9];
    const float* bo = (const float*)d_in[10];
    const float* sinT = (const float*)d_in[11];
    const float* cosT = (const float*)d_in[12];
    float* out = (float*)d_out;

    char* p = (char*)d_ws;
    bf16* hb = (bf16*)p;    p += (size_t)TT * HD * 2;
    bf16* Wcat = (bf16*)p;  p += (size_t)(HD + HD + VD + VD) * HD * 2;
    bf16* WoT = (bf16*)p;   p += (size_t)HD * VD * 2;
    bf16* qr = (bf16*)p;    p += (size_t)TT * HD * 2;
    bf16* kr = (bf16*)p;    p += (size_t)TT * HD * 2;
    bf16* vT = (bf16*)p;    p += (size_t)VD * TT * 2;
    bf16* sg = (bf16*)p;    p += (size_t)TT * VD * 2;
    bf16* po0 = (bf16*)p;   p += (size_t)TT * VD * 2;
    bf16* po1 = (bf16*)p;   p += (size_t)TT * VD * 2;
    float* pr0 = (float*)p; p += (size_t)NH * TT * 4;
    float* pr1 = (float*)p; p += (size_t)NH * TT * 4;
    bf16* gated = (bf16*)p; p += (size_t)TT * VD * 2;
    bf16* outp = (bf16*)p;  p += (size_t)4 * TT * HD * 2;

    // 1) weight transposes + hidden convert (single launch)
    transpose_all_k<<<8704, 256, 0, stream>>>(Wq, Wk, Wv, Wg, Wo, Wcat, WoT, hidden, hb);

    // 2) fused QKVG projection (8-phase 256x192); V written transposed in-epilogue
    gemm_qkvg_k<<<512, 512, 0, stream>>>(hb, Wcat, bq, bk, bvp, bg, sinT, cosT,
                                         qr, kr, vT, sg);

    // 3) fused causal retention + PV (default grid decode — best measured)
    retention_fused_k<<<dim3(8, 2, NH), 512, 0, stream>>>(qr, kr, vT, po0, po1, pr0, pr1);

    // 4) combine + groupnorm + gate, then output projection (8-phase, K-split x4)
    ln_gate_k<<<TT * NH / 4, 256, 0, stream>>>(po0, po1, pr0, pr1, sg, gated);
    gemm_out_k<<<256, 512, 0, stream>>>(gated, WoT, outp);
    combine_out_k<<<TT * HD / 1024, 256, 0, stream>>>(outp, bo, out);
}